// Round 3
// baseline (6698.877 us; speedup 1.0000x reference)
//
#include <hip/hip_runtime.h>
#include <stdint.h>

typedef unsigned short u16;
typedef unsigned int u32;
typedef __attribute__((ext_vector_type(8))) short short8;
typedef __attribute__((ext_vector_type(4))) float floatx4;

#define DEV __device__ __forceinline__

DEV u16 f2bf(float f) {
  u32 u = __float_as_uint(f);
  u32 r = (u + 0x7FFFu + ((u >> 16) & 1u)) >> 16;  // RNE
  return (u16)r;
}
DEV u32 pack2(float a, float b) { return (u32)f2bf(a) | ((u32)f2bf(b) << 16); }

// ---------------------------------------------------------------------------
// fp32 tiled GEMM (small-M path): 64x64 tile, BK=16, 256 threads, 4x4/thread.
// Used only for the 512-row decoder-table GEMMs (grid too small for 128 tile).
// EPI: 0 = +bias, 1 = tanh(+bias), 2 = dist epilogue xnorm[m]+bias[n]-2*acc
// BT:  B source is [N,K] row-major (B transposed)
// ---------------------------------------------------------------------------
template<int EPI, int BT>
__global__ __launch_bounds__(256) void gemm_f32(
    const float* __restrict__ A, const float* __restrict__ Bsrc,
    const float* __restrict__ bias, const float* __restrict__ xnorm,
    float* __restrict__ C, int M, int N, int Kd) {
  __shared__ float As[16][68];
  __shared__ float Bs[16][68];
  int tid = threadIdx.x;
  int nbm = M >> 6, nbn = N >> 6;
  const int GM = 8;  // L2 swizzle group
  int pid = blockIdx.x;
  int gsz = GM * nbn;
  int gid = pid / gsz;
  int first = gid * GM;
  int rem = nbm - first;
  int g = rem < GM ? rem : GM;
  int pm = first + (pid % g);
  int pn = (pid % gsz) / g;
  int m0 = pm << 6, n0 = pn << 6;
  int ty = tid >> 4, tx = tid & 15;
  int ar = tid >> 2, ak = (tid & 3) << 2;
  float accT[4][4] = {};
  for (int k0 = 0; k0 < Kd; k0 += 16) {
    float4 av = *(const float4*)(A + (size_t)(m0 + ar) * Kd + k0 + ak);
    As[ak + 0][ar] = av.x; As[ak + 1][ar] = av.y;
    As[ak + 2][ar] = av.z; As[ak + 3][ar] = av.w;
    if (BT) {
      float4 bv = *(const float4*)(Bsrc + (size_t)(n0 + ar) * Kd + k0 + ak);
      Bs[ak + 0][ar] = bv.x; Bs[ak + 1][ar] = bv.y;
      Bs[ak + 2][ar] = bv.z; Bs[ak + 3][ar] = bv.w;
    } else {
      int kr = tid >> 4, n4 = (tid & 15) << 2;
      *(float4*)&Bs[kr][n4] = *(const float4*)(Bsrc + (size_t)(k0 + kr) * N + n0 + n4);
    }
    __syncthreads();
    float acc[4][4] = {};
#pragma unroll
    for (int kk = 0; kk < 16; ++kk) {
      float4 a4 = *(float4*)&As[kk][ty << 2];
      float4 b4 = *(float4*)&Bs[kk][tx << 2];
      float ax[4] = {a4.x, a4.y, a4.z, a4.w};
      float bx[4] = {b4.x, b4.y, b4.z, b4.w};
#pragma unroll
      for (int i = 0; i < 4; ++i)
#pragma unroll
        for (int j = 0; j < 4; ++j) acc[i][j] = fmaf(ax[i], bx[j], acc[i][j]);
    }
#pragma unroll
    for (int i = 0; i < 4; ++i)
#pragma unroll
      for (int j = 0; j < 4; ++j) accT[i][j] += acc[i][j];
    __syncthreads();
  }
  int cbi = n0 + (tx << 2);
  float4 bb = *(const float4*)(bias + cbi);
  float bx[4] = {bb.x, bb.y, bb.z, bb.w};
#pragma unroll
  for (int i = 0; i < 4; ++i) {
    int row = m0 + (ty << 2) + i;
    float v[4];
    if (EPI == 2) {
      float xn = xnorm[row];
#pragma unroll
      for (int j = 0; j < 4; ++j) v[j] = xn + bx[j] - 2.0f * accT[i][j];
    } else {
#pragma unroll
      for (int j = 0; j < 4; ++j) {
        float t = accT[i][j] + bx[j];
        v[j] = (EPI == 1) ? tanhf(t) : t;
      }
    }
    float4 o; o.x = v[0]; o.y = v[1]; o.z = v[2]; o.w = v[3];
    *(float4*)(C + (size_t)row * N + cbi) = o;
  }
}

// ---------------------------------------------------------------------------
// fp32 tiled GEMM (big-M path): 128x128 tile, BK=32, 256 threads, 8x8/thread.
// - LDS tiles [k][m]/[k][n] with XOR swizzle g(k)=((k>>3)&3)<<3 on the column
//   index: transpose staging writes become 2-way (free), frag reads stay
//   conflict-free. All swizzled addresses precomputed outside the K loop.
// - Async-stage split: global loads for tile t+1 issued right after the first
//   barrier; ds_writes land next iteration (HBM latency hides under compute).
// - FOLD=1: two-level per-32-K chunk accumulation (argmin-grade accuracy;
//   used ONLY for the dist GEMM enc@cb^T). FOLD=0: single-level acc (encoder
//   GEMMs; enc-side errors cancel in argmin comparisons since the ||enc||^2
//   term is shared across codebook columns — the perturbed enc point's exact
//   nearest neighbor is what argmin returns either way).
// ---------------------------------------------------------------------------
#define GEMM_INNER(ACCV)                                                       \
  _Pragma("unroll") for (int kk = 0; kk < 32; ++kk) {                          \
    const int s_ = (kk >> 3) & 3;                                              \
    float4 a0 = *(const float4*)((const char*)As + kk * 528 + baseA[s_]);      \
    float4 a1 = *(const float4*)((const char*)As + kk * 528 + 256 + baseA[s_]);\
    float4 b0 = *(const float4*)((const char*)Bs + kk * 528 + baseB[s_]);      \
    float4 b1 = *(const float4*)((const char*)Bs + kk * 528 + 256 + baseB[s_]);\
    float ax[8] = {a0.x, a0.y, a0.z, a0.w, a1.x, a1.y, a1.z, a1.w};            \
    float bx[8] = {b0.x, b0.y, b0.z, b0.w, b1.x, b1.y, b1.z, b1.w};            \
    _Pragma("unroll") for (int i_ = 0; i_ < 8; ++i_)                           \
      _Pragma("unroll") for (int j_ = 0; j_ < 8; ++j_)                         \
        ACCV[i_][j_] = fmaf(ax[i_], bx[j_], ACCV[i_][j_]);                     \
  }

template<int EPI, int BT, int FOLD>
__global__ __launch_bounds__(256, FOLD ? 2 : 3) void gemm_f32_big(
    const float* __restrict__ A, const float* __restrict__ Bsrc,
    const float* __restrict__ bias, const float* __restrict__ xnorm,
    float* __restrict__ C, int M, int N, int Kd) {
  __shared__ float As[32][132];  // [k][m^g(k)], 528B rows (16B-aligned)
  __shared__ float Bs[32][132];  // [k][n^g(k)]
  int tid = threadIdx.x;
  int nbm = M >> 7, nbn = N >> 7;
  const int GM = 8;  // L2 swizzle group
  int pid = blockIdx.x;
  int gsz = GM * nbn;
  int gid = pid / gsz;
  int first = gid * GM;
  int rem = nbm - first;
  int g = rem < GM ? rem : GM;
  int pm = first + (pid % g);
  int pn = (pid % gsz) / g;
  int m0 = pm << 7, n0 = pn << 7;
  int ty = tid >> 4, tx = tid & 15;

  // fragment read byte-offsets for the 4 swizzle classes (kk>>3)&3
  int baseA[4], baseB[4];
#pragma unroll
  for (int s = 0; s < 4; ++s) {
    baseA[s] = (((ty << 2) ^ (s << 3))) << 2;
    baseB[s] = (((tx << 2) ^ (s << 3))) << 2;
  }

  // staging addresses (k0-invariant) + global source pointers
  int awr[4], bwr[4];
  const float* pa_src[4];
  const float* pb_src[4];
#pragma unroll
  for (int l = 0; l < 4; ++l) {
    int idx = tid + (l << 8);
    int r = idx >> 3, kc = (idx & 7) << 2;
    int swa = ((kc >> 3) & 3) << 3;
    awr[l] = kc * 528 + ((r ^ swa) << 2);
    pa_src[l] = A + (size_t)(m0 + r) * Kd + kc;
    if (BT) {
      bwr[l] = kc * 528 + ((r ^ swa) << 2);
      pb_src[l] = Bsrc + (size_t)(n0 + r) * Kd + kc;
    } else {
      int kr = idx >> 5, nc = (idx & 31) << 2;
      int swb = ((kr >> 3) & 3) << 3;
      bwr[l] = kr * 528 + ((nc ^ swb) << 2);
      pb_src[l] = Bsrc + (size_t)kr * N + n0 + nc;
    }
  }

  float accT[8][8] = {};
  float4 va[4], vb[4];
#pragma unroll
  for (int l = 0; l < 4; ++l) {
    va[l] = *(const float4*)pa_src[l];
    vb[l] = *(const float4*)pb_src[l];
  }
  int nk = Kd >> 5;
  for (int t = 0; t < nk; ++t) {
    // ---- write staged tile to LDS (swizzled) ----
#pragma unroll
    for (int l = 0; l < 4; ++l) {
      char* wa = (char*)As + awr[l];
      *(float*)(wa + 0)    = va[l].x;
      *(float*)(wa + 528)  = va[l].y;
      *(float*)(wa + 1056) = va[l].z;
      *(float*)(wa + 1584) = va[l].w;
      if (BT) {
        char* wb = (char*)Bs + bwr[l];
        *(float*)(wb + 0)    = vb[l].x;
        *(float*)(wb + 528)  = vb[l].y;
        *(float*)(wb + 1056) = vb[l].z;
        *(float*)(wb + 1584) = vb[l].w;
      } else {
        *(float4*)((char*)Bs + bwr[l]) = vb[l];
      }
    }
    __syncthreads();
    // ---- prefetch next tile (latency hides under compute) ----
    if (t + 1 < nk) {
#pragma unroll
      for (int l = 0; l < 4; ++l) {
        pa_src[l] += 32;
        va[l] = *(const float4*)pa_src[l];
        pb_src[l] += BT ? (size_t)32 : (size_t)32 * N;
        vb[l] = *(const float4*)pb_src[l];
      }
    }
    // ---- compute ----
    if (FOLD) {
      float acc[8][8] = {};
      GEMM_INNER(acc)
#pragma unroll
      for (int i = 0; i < 8; ++i)
#pragma unroll
        for (int j = 0; j < 8; ++j) accT[i][j] += acc[i][j];
    } else {
      GEMM_INNER(accT)
    }
    __syncthreads();
  }

  float4 bb0 = *(const float4*)(bias + n0 + (tx << 2));
  float4 bb1 = *(const float4*)(bias + n0 + 64 + (tx << 2));
  float bxv[8] = {bb0.x, bb0.y, bb0.z, bb0.w, bb1.x, bb1.y, bb1.z, bb1.w};
#pragma unroll
  for (int hi = 0; hi < 2; ++hi)
#pragma unroll
    for (int i = 0; i < 4; ++i) {
      int row = m0 + hi * 64 + (ty << 2) + i;
      float xn = 0.0f;
      if (EPI == 2) xn = xnorm[row];
#pragma unroll
      for (int hj = 0; hj < 2; ++hj) {
        float v[4];
#pragma unroll
        for (int j = 0; j < 4; ++j) {
          float t = accT[hi * 4 + i][hj * 4 + j];
          if (EPI == 2) {
            v[j] = xn + bxv[hj * 4 + j] - 2.0f * t;
          } else {
            t += bxv[hj * 4 + j];
            v[j] = (EPI == 1) ? tanhf(t) : t;
          }
        }
        float4 o; o.x = v[0]; o.y = v[1]; o.z = v[2]; o.w = v[3];
        *(float4*)(C + (size_t)row * N + n0 + hj * 64 + (tx << 2)) = o;
      }
    }
}

// ---------------------------------------------------------------------------
// bf16 MFMA GEMM: 128x128 tile, BK=32, 4 waves, each wave 64x64 via 4x4 of
// 16x16x32 mfma. B is pre-transposed bf16 [N,K]. LDS stride 40 ushorts (80 B:
// 16B-aligned rows, 2-way-max bank aliasing on b128 frag reads = free).
// ASRC: 0 = A is bf16 [M,K]; 2 = dual f32 sources (X for k<K1, A2 for k>=K1)
// ---------------------------------------------------------------------------
template<int ASRC, int TANH, int OUTBF>
__global__ __launch_bounds__(256) void gemm_bf16(
    const void* __restrict__ Ap, const float* __restrict__ A2,
    const u16* __restrict__ Bt, const float* __restrict__ bias,
    void* __restrict__ Cp, int M, int N, int Kd, int K1) {
  __shared__ u16 As[128 * 40];
  __shared__ u16 Bs[128 * 40];
  int tid = threadIdx.x;
  int nbm = M >> 7, nbn = N >> 7;
  const int GM = 16;  // L2 swizzle group
  int pid = blockIdx.x;
  int gsz = GM * nbn;
  int gid = pid / gsz;
  int first = gid * GM;
  int rem = nbm - first;
  int g = rem < GM ? rem : GM;
  int pm = first + (pid % g);
  int pn = (pid % gsz) / g;
  int m0 = pm << 7, n0 = pn << 7;
  int w = tid >> 6, lane = tid & 63, l15 = lane & 15, kq = lane >> 4;
  int wm = (w >> 1) << 6, wn = (w & 1) << 6;
  floatx4 acc[4][4];
#pragma unroll
  for (int i = 0; i < 4; ++i)
#pragma unroll
    for (int j = 0; j < 4; ++j) acc[i][j] = (floatx4){0.f, 0.f, 0.f, 0.f};
  int aoff = (wm + l15) * 40 + (kq << 3);
  int boff = (wn + l15) * 40 + (kq << 3);
  for (int k0 = 0; k0 < Kd; k0 += 32) {
#pragma unroll
    for (int l = 0; l < 4; ++l) {
      int idx = tid + (l << 8);
      int row = idx >> 3;
      int c = (idx & 7) << 2;
      uint2 av;
      if (ASRC == 0) {
        av = *(const uint2*)((const u16*)Ap + (size_t)(m0 + row) * Kd + k0 + c);
      } else {
        const float* s; int ld, kk;
        if (k0 < K1) { s = (const float*)Ap; ld = K1; kk = k0; }
        else { s = A2; ld = Kd - K1; kk = k0 - K1; }
        float4 v = *(const float4*)(s + (size_t)(m0 + row) * ld + kk + c);
        av.x = pack2(v.x, v.y);
        av.y = pack2(v.z, v.w);
      }
      *(uint2*)&As[row * 40 + c] = av;
      *(uint2*)&Bs[row * 40 + c] =
          *(const uint2*)(Bt + (size_t)(n0 + row) * Kd + k0 + c);
    }
    __syncthreads();
    short8 af[4], bf[4];
#pragma unroll
    for (int i = 0; i < 4; ++i) {
      af[i] = *(const short8*)&As[aoff + i * (16 * 40)];
      bf[i] = *(const short8*)&Bs[boff + i * (16 * 40)];
    }
#pragma unroll
    for (int mi = 0; mi < 4; ++mi)
#pragma unroll
      for (int ni = 0; ni < 4; ++ni)
        acc[mi][ni] = __builtin_amdgcn_mfma_f32_16x16x32_bf16(
            af[mi], bf[ni], acc[mi][ni], 0, 0, 0);
    __syncthreads();
  }
  float bcol[4];
#pragma unroll
  for (int ni = 0; ni < 4; ++ni) bcol[ni] = bias[n0 + wn + (ni << 4) + l15];
#pragma unroll
  for (int mi = 0; mi < 4; ++mi)
#pragma unroll
    for (int ni = 0; ni < 4; ++ni)
#pragma unroll
      for (int r = 0; r < 4; ++r) {
        int row = m0 + wm + (mi << 4) + (kq << 2) + r;  // C/D: row=(lane>>4)*4+reg
        int col = n0 + wn + (ni << 4) + l15;            //      col=lane&15
        float v = acc[mi][ni][r] + bcol[ni];
        if (TANH) v = tanhf(v);
        if (OUTBF) ((u16*)Cp)[(size_t)row * N + col] = f2bf(v);
        else ((float*)Cp)[(size_t)row * N + col] = v;
      }
}

// f32 [K,N] -> bf16 [N,K] transpose+convert (32x32 LDS tile)
__global__ __launch_bounds__(256) void transpose_cvt(
    const float* __restrict__ in, u16* __restrict__ out, int K, int N) {
  __shared__ float t[32][33];
  int tid = threadIdx.x;
  int bx = blockIdx.x, by = blockIdx.y;  // bx: n-block, by: k-block
  int r = tid >> 3, c4 = (tid & 7) << 2;
  float4 v = *(const float4*)(in + (size_t)(by * 32 + r) * N + bx * 32 + c4);
  t[r][c4 + 0] = v.x; t[r][c4 + 1] = v.y; t[r][c4 + 2] = v.z; t[r][c4 + 3] = v.w;
  __syncthreads();
  uint2 o;
  o.x = pack2(t[c4 + 0][r], t[c4 + 1][r]);
  o.y = pack2(t[c4 + 2][r], t[c4 + 3][r]);
  *(uint2*)(out + (size_t)(bx * 32 + r) * K + by * 32 + c4) = o;
}

// per-row sum of squares; one wave per row
__global__ __launch_bounds__(256) void rownorm_k(
    const float* __restrict__ src, float* __restrict__ out, int cols) {
  int w = threadIdx.x >> 6, lane = threadIdx.x & 63;
  int row = (blockIdx.x << 2) + w;
  const float* p = src + (size_t)row * cols;
  float s = 0.f;
  for (int c = lane; c < cols; c += 64) { float v = p[c]; s = fmaf(v, v, s); }
#pragma unroll
  for (int o = 32; o; o >>= 1) s += __shfl_xor(s, o, 64);
  if (lane == 0) out[row] = s;
}

__global__ void zero_sums(float* p) { if (threadIdx.x < 2) p[threadIdx.x] = 0.f; }

// one wave per row: argmin over 512 dists (first-index tie-break, matching
// jnp.argmin), then commit = ||enc-cb[p]||^2 and recon = ||dx-rect[p]||^2
__global__ __launch_bounds__(256) void argmin_losses(
    const float* __restrict__ dist, const float* __restrict__ enc,
    const float* __restrict__ cb, const float* __restrict__ dx,
    const float* __restrict__ rect, float* __restrict__ prop_out,
    float* __restrict__ sums) {
  int w = threadIdx.x >> 6, lane = threadIdx.x & 63;
  int row = (blockIdx.x << 2) + w;
  const float* drow = dist + (size_t)row * 512;
  float best = 3.4e38f; int bi = 0;
#pragma unroll
  for (int j = 0; j < 8; ++j) {
    int idx = lane + (j << 6);
    float v = drow[idx];
    if (v < best) { best = v; bi = idx; }
  }
#pragma unroll
  for (int o = 32; o; o >>= 1) {
    float ov = __shfl_xor(best, o, 64);
    int oi = __shfl_xor(bi, o, 64);
    if (ov < best || (ov == best && oi < bi)) { best = ov; bi = oi; }
  }
  int p = bi;
  const float* erow = enc + (size_t)row * 1024;
  const float* crow = cb + (size_t)p * 1024;
  const float* xrow = dx + (size_t)row * 1024;
  const float* rrow = rect + (size_t)p * 1024;
  float cs = 0.f, rs = 0.f;
#pragma unroll 4
  for (int c = 0; c < 16; ++c) {
    int col = lane + (c << 6);
    float d1 = erow[col] - crow[col]; cs = fmaf(d1, d1, cs);
    float d2 = xrow[col] - rrow[col]; rs = fmaf(d2, d2, rs);
  }
#pragma unroll
  for (int o = 32; o; o >>= 1) {
    cs += __shfl_xor(cs, o, 64);
    rs += __shfl_xor(rs, o, 64);
  }
  if (lane == 0) {
    atomicAdd(&sums[0], rs);
    atomicAdd(&sums[1], cs);
    prop_out[row] = (float)p;
  }
}

// one wave per row: loss_pi = sum_j 1/(exp(logp)+0.1); loss = loss_pi*total
__global__ __launch_bounds__(256) void finalize_k(
    const float* __restrict__ Aa, const float* __restrict__ mu,
    const float* __restrict__ log_std, const float* __restrict__ sums,
    float* __restrict__ loss, float* __restrict__ losspi,
    float* __restrict__ total_out) {
  int w = threadIdx.x >> 6, lane = threadIdx.x & 63;
  int row = (blockIdx.x << 2) + w;
  // total = recon + vq + commit; vq==commit in forward value
  float total = (sums[0] + 2.0f * sums[1]) * (1.0f / 33554432.0f);
  float s = 0.f;
#pragma unroll
  for (int c = 0; c < 4; ++c) {
    int j = lane + (c << 6);
    float ls = log_std[j];
    float istd = expf(-ls);
    float z = (Aa[(size_t)row * 256 + j] - mu[(size_t)row * 256 + j]) * istd;
    float lp = -0.5f * z * z - ls - 0.91893853320467274f;  // 0.5*log(2*pi)
    s += 1.0f / (expf(lp) + 0.1f);
  }
#pragma unroll
  for (int o = 32; o; o >>= 1) s += __shfl_xor(s, o, 64);
  if (lane == 0) { losspi[row] = s; loss[row] = s * total; }
  if (blockIdx.x == 0 && threadIdx.x == 0) total_out[0] = total;
}

// ---------------------------------------------------------------------------
extern "C" void kernel_launch(void* const* d_in, const int* in_sizes, int n_in,
                              void* d_out, int out_size, void* d_ws,
                              size_t ws_size, hipStream_t stream) {
  (void)in_sizes; (void)n_in; (void)out_size; (void)ws_size;
  const float* X = (const float*)d_in[0];
  const float* DX = (const float*)d_in[1];
  const float* Aa = (const float*)d_in[2];
  const float* enc_w1 = (const float*)d_in[3];
  const float* enc_b1 = (const float*)d_in[4];
  const float* enc_w2 = (const float*)d_in[5];
  const float* enc_b2 = (const float*)d_in[6];
  const float* prenet_w = (const float*)d_in[7];
  const float* prenet_b = (const float*)d_in[8];
  const float* cb = (const float*)d_in[9];
  const float* postnet_w = (const float*)d_in[10];
  const float* postnet_b = (const float*)d_in[11];
  const float* dec_w1 = (const float*)d_in[12];
  const float* dec_b1 = (const float*)d_in[13];
  const float* dec_w2 = (const float*)d_in[14];
  const float* dec_b2 = (const float*)d_in[15];
  const float* dec_w3 = (const float*)d_in[16];
  const float* dec_b3 = (const float*)d_in[17];
  const float* act_w1 = (const float*)d_in[18];
  const float* act_b1 = (const float*)d_in[19];
  const float* act_w2 = (const float*)d_in[20];
  const float* act_b2 = (const float*)d_in[21];
  const float* act_w3 = (const float*)d_in[22];
  const float* act_b3 = (const float*)d_in[23];
  const float* log_std = (const float*)d_in[24];

  float* outf = (float*)d_out;
  const size_t MB = 1ull << 20;
  // Scratch inside the d_out X-slot [65536, 65536+33554432) floats (128 MB);
  // all of it is dead before the final X d2d copy overwrites it.
  char* ox = (char*)(outf + 65536);
  float* dist = (float*)(ox);               // 64 MB, [B,512] f32
  u16* w1T = (u16*)(ox + 64 * MB);          // 6 MB  [2048,1536] bf16
  u16* w2T = (u16*)(ox + 70 * MB);          // 8 MB  [2048,2048] bf16
  u16* w3T = (u16*)(ox + 78 * MB);          // 1 MB  [256,2048] bf16
  float* t0 = (float*)(ox + 79 * MB);       // 2 MB  [512,1024]
  float* d1t = (float*)(ox + 81 * MB);      // 4 MB  [512,2048]
  float* d2t = (float*)(ox + 85 * MB);      // 4 MB  [512,2048]
  float* rect = (float*)(ox + 89 * MB);     // 2 MB  [512,1024] decoder table
  float* mu = (float*)(ox + 91 * MB);       // 32 MB [B,256] f32
  float* cbnorm = (float*)(ox + 123 * MB);  // 2 KB
  float* xnorm = (float*)(ox + 123 * MB + 8192);            // 128 KB
  float* sums = (float*)(ox + 123 * MB + 8192 + 131072);    // 8 B {recon,commit}

  // Workspace (peak 256 MB) with lifetime-based reuse:
  char* wsb = (char*)d_ws;
  float* h2 = (float*)(wsb);              // [0,128) MB, live L5->L6
  float* h1 = (float*)(wsb + 128 * MB);   // [128,192) MB, live L4->L5
  float* enc = (float*)(wsb + 128 * MB);  // [128,256) MB, live L6->argmin (h1 dead)
  u16* a1 = (u16*)(wsb);                  // [0,128) MB bf16 (h2 dead)
  u16* a2 = (u16*)(wsb + 128 * MB);       // [128,256) MB bf16 (enc dead)

  zero_sums<<<1, 64, 0, stream>>>(sums);
  rownorm_k<<<128, 256, 0, stream>>>(cb, cbnorm, 1024);
  transpose_cvt<<<dim3(64, 48), 256, 0, stream>>>(act_w1, w1T, 1536, 2048);
  transpose_cvt<<<dim3(64, 64), 256, 0, stream>>>(act_w2, w2T, 2048, 2048);
  transpose_cvt<<<dim3(8, 64), 256, 0, stream>>>(act_w3, w3T, 2048, 256);

  // encoder chain (fp32; single-level acc — enc errors cancel in argmin)
  gemm_f32_big<1, 0, 0><<<256 * 4, 256, 0, stream>>>(DX, enc_w1, enc_b1, nullptr, h1, 32768, 512, 1024);
  gemm_f32_big<1, 0, 0><<<256 * 8, 256, 0, stream>>>(h1, enc_w2, enc_b2, nullptr, h2, 32768, 1024, 512);
  gemm_f32_big<0, 0, 0><<<256 * 8, 256, 0, stream>>>(h2, prenet_w, prenet_b, nullptr, enc, 32768, 1024, 1024);
  rownorm_k<<<8192, 256, 0, stream>>>(enc, xnorm, 1024);
  // dist = xnorm[m] + cbnorm[n] - 2*enc@cb^T  (fp32, two-level accumulation)
  gemm_f32_big<2, 1, 1><<<256 * 4, 256, 0, stream>>>(enc, cb, cbnorm, xnorm, dist, 32768, 512, 1024);

  // decoder evaluated on the 512 codebook rows only (st_q == quantized fwd)
  gemm_f32<1, 0><<<8 * 16, 256, 0, stream>>>(cb, postnet_w, postnet_b, nullptr, t0, 512, 1024, 1024);
  gemm_f32<1, 0><<<8 * 32, 256, 0, stream>>>(t0, dec_w1, dec_b1, nullptr, d1t, 512, 2048, 1024);
  gemm_f32<1, 0><<<8 * 32, 256, 0, stream>>>(d1t, dec_w2, dec_b2, nullptr, d2t, 512, 2048, 2048);
  gemm_f32<0, 0><<<8 * 16, 256, 0, stream>>>(d2t, dec_w3, dec_b3, nullptr, rect, 512, 1024, 2048);

  // argmin + proposal + recon/commit sums
  argmin_losses<<<8192, 256, 0, stream>>>(dist, enc, cb, DX, rect,
                                          outf + 33619968, sums);

  // actor (bf16 MFMA); A of act1 = [X | dist] via dual-f32 loader
  gemm_bf16<2, 1, 1><<<4096, 256, 0, stream>>>(X, dist, w1T, act_b1, a1, 32768, 2048, 1536, 1024);
  gemm_bf16<0, 1, 1><<<4096, 256, 0, stream>>>(a1, nullptr, w2T, act_b2, a2, 32768, 2048, 2048, 0);
  gemm_bf16<0, 0, 0><<<512, 256, 0, stream>>>(a2, nullptr, w3T, act_b3, mu, 32768, 256, 2048, 0);

  finalize_k<<<8192, 256, 0, stream>>>(Aa, mu, log_std, sums, outf,
                                       outf + 32768, outf + 33652736);
  // X passthrough (overwrites the out-scratch region, must be last)
  hipMemcpyAsync(outf + 65536, X, 134217728ull, hipMemcpyDeviceToDevice, stream);
}

// Round 4
// 4917.545 us; speedup vs baseline: 1.3622x; 1.3622x over previous
//
#include <hip/hip_runtime.h>
#include <stdint.h>

typedef unsigned short u16;
typedef unsigned int u32;
typedef __attribute__((ext_vector_type(8))) short short8;
typedef __attribute__((ext_vector_type(4))) float floatx4;

#define DEV __device__ __forceinline__

DEV u16 f2bf(float f) {
  u32 u = __float_as_uint(f);
  u32 r = (u + 0x7FFFu + ((u >> 16) & 1u)) >> 16;  // RNE
  return (u16)r;
}
DEV u32 pack2(float a, float b) { return (u32)f2bf(a) | ((u32)f2bf(b) << 16); }

// ---------------------------------------------------------------------------
// fp32 tiled GEMM (small-M path): 64x64 tile, BK=16, 256 threads, 4x4/thread.
// Used only for the 512-row decoder-table GEMMs (grid too small for 128 tile).
// EPI: 0 = +bias, 1 = tanh(+bias), 2 = dist epilogue xnorm[m]+bias[n]-2*acc
// BT:  B source is [N,K] row-major (B transposed)
// ---------------------------------------------------------------------------
template<int EPI, int BT>
__global__ __launch_bounds__(256) void gemm_f32(
    const float* __restrict__ A, const float* __restrict__ Bsrc,
    const float* __restrict__ bias, const float* __restrict__ xnorm,
    float* __restrict__ C, int M, int N, int Kd) {
  __shared__ float As[16][68];
  __shared__ float Bs[16][68];
  int tid = threadIdx.x;
  int nbm = M >> 6, nbn = N >> 6;
  const int GM = 8;  // L2 swizzle group
  int pid = blockIdx.x;
  int gsz = GM * nbn;
  int gid = pid / gsz;
  int first = gid * GM;
  int rem = nbm - first;
  int g = rem < GM ? rem : GM;
  int pm = first + (pid % g);
  int pn = (pid % gsz) / g;
  int m0 = pm << 6, n0 = pn << 6;
  int ty = tid >> 4, tx = tid & 15;
  int ar = tid >> 2, ak = (tid & 3) << 2;
  float accT[4][4] = {};
  for (int k0 = 0; k0 < Kd; k0 += 16) {
    float4 av = *(const float4*)(A + (size_t)(m0 + ar) * Kd + k0 + ak);
    As[ak + 0][ar] = av.x; As[ak + 1][ar] = av.y;
    As[ak + 2][ar] = av.z; As[ak + 3][ar] = av.w;
    if (BT) {
      float4 bv = *(const float4*)(Bsrc + (size_t)(n0 + ar) * Kd + k0 + ak);
      Bs[ak + 0][ar] = bv.x; Bs[ak + 1][ar] = bv.y;
      Bs[ak + 2][ar] = bv.z; Bs[ak + 3][ar] = bv.w;
    } else {
      int kr = tid >> 4, n4 = (tid & 15) << 2;
      *(float4*)&Bs[kr][n4] = *(const float4*)(Bsrc + (size_t)(k0 + kr) * N + n0 + n4);
    }
    __syncthreads();
    float acc[4][4] = {};
#pragma unroll
    for (int kk = 0; kk < 16; ++kk) {
      float4 a4 = *(float4*)&As[kk][ty << 2];
      float4 b4 = *(float4*)&Bs[kk][tx << 2];
      float ax[4] = {a4.x, a4.y, a4.z, a4.w};
      float bx[4] = {b4.x, b4.y, b4.z, b4.w};
#pragma unroll
      for (int i = 0; i < 4; ++i)
#pragma unroll
        for (int j = 0; j < 4; ++j) acc[i][j] = fmaf(ax[i], bx[j], acc[i][j]);
    }
#pragma unroll
    for (int i = 0; i < 4; ++i)
#pragma unroll
      for (int j = 0; j < 4; ++j) accT[i][j] += acc[i][j];
    __syncthreads();
  }
  int cbi = n0 + (tx << 2);
  float4 bb = *(const float4*)(bias + cbi);
  float bx[4] = {bb.x, bb.y, bb.z, bb.w};
#pragma unroll
  for (int i = 0; i < 4; ++i) {
    int row = m0 + (ty << 2) + i;
    float v[4];
    if (EPI == 2) {
      float xn = xnorm[row];
#pragma unroll
      for (int j = 0; j < 4; ++j) v[j] = xn + bx[j] - 2.0f * accT[i][j];
    } else {
#pragma unroll
      for (int j = 0; j < 4; ++j) {
        float t = accT[i][j] + bx[j];
        v[j] = (EPI == 1) ? tanhf(t) : t;
      }
    }
    float4 o; o.x = v[0]; o.y = v[1]; o.z = v[2]; o.w = v[3];
    *(float4*)(C + (size_t)row * N + cbi) = o;
  }
}

// ---------------------------------------------------------------------------
// fp32 tiled GEMM (big-M path): 128x128 tile, BK=32, 256 threads, 8x8/thread.
// - LDS tiles [k][m]/[k][n] with XOR swizzle g(k)=((k>>3)&3)<<3 on the column
//   index: transpose staging writes become 2-way (free), frag reads stay
//   conflict-free.
// - Inner loop is a nested STATIC double loop (s_ in 0..3, k2_ in 0..7) so
//   every baseA[s_]/baseB[s_] access is a compile-time index. (Round-3 bug:
//   runtime s_ put these arrays in scratch -> GBs of scratch traffic.)
// - Async-stage split: global loads for tile t+1 issued right after the first
//   barrier; ds_writes land next iteration (HBM latency hides under compute).
// - FOLD=1: two-level per-32-K chunk accumulation (argmin-grade accuracy;
//   used ONLY for the dist GEMM enc@cb^T). FOLD=0: single-level acc (encoder
//   GEMMs; verified passing with identical absmax in round 3).
// - launch_bounds(256,2): cap 256 VGPRs, guarantees no spill (demand ~160/215).
// ---------------------------------------------------------------------------
#define GEMM_INNER(ACCV)                                                       \
  _Pragma("unroll") for (int s_ = 0; s_ < 4; ++s_) {                           \
    _Pragma("unroll") for (int k2_ = 0; k2_ < 8; ++k2_) {                      \
      const int kk_ = s_ * 8 + k2_;                                            \
      float4 a0 = *(const float4*)((const char*)As + kk_ * 528 + baseA[s_]);   \
      float4 a1 = *(const float4*)((const char*)As + kk_ * 528 + 256 + baseA[s_]); \
      float4 b0 = *(const float4*)((const char*)Bs + kk_ * 528 + baseB[s_]);   \
      float4 b1 = *(const float4*)((const char*)Bs + kk_ * 528 + 256 + baseB[s_]); \
      float ax[8] = {a0.x, a0.y, a0.z, a0.w, a1.x, a1.y, a1.z, a1.w};          \
      float bx[8] = {b0.x, b0.y, b0.z, b0.w, b1.x, b1.y, b1.z, b1.w};          \
      _Pragma("unroll") for (int i_ = 0; i_ < 8; ++i_)                         \
        _Pragma("unroll") for (int j_ = 0; j_ < 8; ++j_)                       \
          ACCV[i_][j_] = fmaf(ax[i_], bx[j_], ACCV[i_][j_]);                   \
    }                                                                          \
  }

template<int EPI, int BT, int FOLD>
__global__ __launch_bounds__(256, 2) void gemm_f32_big(
    const float* __restrict__ A, const float* __restrict__ Bsrc,
    const float* __restrict__ bias, const float* __restrict__ xnorm,
    float* __restrict__ C, int M, int N, int Kd) {
  __shared__ float As[32][132];  // [k][m^g(k)], 528B rows (16B-aligned)
  __shared__ float Bs[32][132];  // [k][n^g(k)]
  int tid = threadIdx.x;
  int nbm = M >> 7, nbn = N >> 7;
  const int GM = 8;  // L2 swizzle group
  int pid = blockIdx.x;
  int gsz = GM * nbn;
  int gid = pid / gsz;
  int first = gid * GM;
  int rem = nbm - first;
  int g = rem < GM ? rem : GM;
  int pm = first + (pid % g);
  int pn = (pid % gsz) / g;
  int m0 = pm << 7, n0 = pn << 7;
  int ty = tid >> 4, tx = tid & 15;

  // fragment read byte-offsets for the 4 swizzle classes (kk>>3)&3
  int baseA[4], baseB[4];
#pragma unroll
  for (int s = 0; s < 4; ++s) {
    baseA[s] = (((ty << 2) ^ (s << 3))) << 2;
    baseB[s] = (((tx << 2) ^ (s << 3))) << 2;
  }

  // staging addresses (k0-invariant) + global source pointers
  int awr[4], bwr[4];
  const float* pa_src[4];
  const float* pb_src[4];
#pragma unroll
  for (int l = 0; l < 4; ++l) {
    int idx = tid + (l << 8);
    int r = idx >> 3, kc = (idx & 7) << 2;
    int swa = ((kc >> 3) & 3) << 3;
    awr[l] = kc * 528 + ((r ^ swa) << 2);
    pa_src[l] = A + (size_t)(m0 + r) * Kd + kc;
    if (BT) {
      bwr[l] = kc * 528 + ((r ^ swa) << 2);
      pb_src[l] = Bsrc + (size_t)(n0 + r) * Kd + kc;
    } else {
      int kr = idx >> 5, nc = (idx & 31) << 2;
      int swb = ((kr >> 3) & 3) << 3;
      bwr[l] = kr * 528 + ((nc ^ swb) << 2);
      pb_src[l] = Bsrc + (size_t)kr * N + n0 + nc;
    }
  }

  float accT[8][8] = {};
  float4 va[4], vb[4];
#pragma unroll
  for (int l = 0; l < 4; ++l) {
    va[l] = *(const float4*)pa_src[l];
    vb[l] = *(const float4*)pb_src[l];
  }
  int nk = Kd >> 5;
  for (int t = 0; t < nk; ++t) {
    // ---- write staged tile to LDS (swizzled) ----
#pragma unroll
    for (int l = 0; l < 4; ++l) {
      char* wa = (char*)As + awr[l];
      *(float*)(wa + 0)    = va[l].x;
      *(float*)(wa + 528)  = va[l].y;
      *(float*)(wa + 1056) = va[l].z;
      *(float*)(wa + 1584) = va[l].w;
      if (BT) {
        char* wb = (char*)Bs + bwr[l];
        *(float*)(wb + 0)    = vb[l].x;
        *(float*)(wb + 528)  = vb[l].y;
        *(float*)(wb + 1056) = vb[l].z;
        *(float*)(wb + 1584) = vb[l].w;
      } else {
        *(float4*)((char*)Bs + bwr[l]) = vb[l];
      }
    }
    __syncthreads();
    // ---- prefetch next tile (latency hides under compute) ----
    if (t + 1 < nk) {
#pragma unroll
      for (int l = 0; l < 4; ++l) {
        pa_src[l] += 32;
        va[l] = *(const float4*)pa_src[l];
        pb_src[l] += BT ? (size_t)32 : (size_t)32 * N;
        vb[l] = *(const float4*)pb_src[l];
      }
    }
    // ---- compute ----
    if (FOLD) {
      float acc[8][8] = {};
      GEMM_INNER(acc)
#pragma unroll
      for (int i = 0; i < 8; ++i)
#pragma unroll
        for (int j = 0; j < 8; ++j) accT[i][j] += acc[i][j];
    } else {
      GEMM_INNER(accT)
    }
    __syncthreads();
  }

  float4 bb0 = *(const float4*)(bias + n0 + (tx << 2));
  float4 bb1 = *(const float4*)(bias + n0 + 64 + (tx << 2));
  float bxv[8] = {bb0.x, bb0.y, bb0.z, bb0.w, bb1.x, bb1.y, bb1.z, bb1.w};
#pragma unroll
  for (int hi = 0; hi < 2; ++hi)
#pragma unroll
    for (int i = 0; i < 4; ++i) {
      int row = m0 + hi * 64 + (ty << 2) + i;
      float xn = 0.0f;
      if (EPI == 2) xn = xnorm[row];
#pragma unroll
      for (int hj = 0; hj < 2; ++hj) {
        float v[4];
#pragma unroll
        for (int j = 0; j < 4; ++j) {
          float t = accT[hi * 4 + i][hj * 4 + j];
          if (EPI == 2) {
            v[j] = xn + bxv[hj * 4 + j] - 2.0f * t;
          } else {
            t += bxv[hj * 4 + j];
            v[j] = (EPI == 1) ? tanhf(t) : t;
          }
        }
        float4 o; o.x = v[0]; o.y = v[1]; o.z = v[2]; o.w = v[3];
        *(float4*)(C + (size_t)row * N + n0 + hj * 64 + (tx << 2)) = o;
      }
    }
}

// ---------------------------------------------------------------------------
// bf16 MFMA GEMM: 128x128 tile, BK=32, 4 waves, each wave 64x64 via 4x4 of
// 16x16x32 mfma. B is pre-transposed bf16 [N,K]. LDS stride 40 ushorts (80 B:
// 16B-aligned rows, 2-way-max bank aliasing on b128 frag reads = free).
// ASRC: 0 = A is bf16 [M,K]; 2 = dual f32 sources (X for k<K1, A2 for k>=K1)
// ---------------------------------------------------------------------------
template<int ASRC, int TANH, int OUTBF>
__global__ __launch_bounds__(256) void gemm_bf16(
    const void* __restrict__ Ap, const float* __restrict__ A2,
    const u16* __restrict__ Bt, const float* __restrict__ bias,
    void* __restrict__ Cp, int M, int N, int Kd, int K1) {
  __shared__ u16 As[128 * 40];
  __shared__ u16 Bs[128 * 40];
  int tid = threadIdx.x;
  int nbm = M >> 7, nbn = N >> 7;
  const int GM = 16;  // L2 swizzle group
  int pid = blockIdx.x;
  int gsz = GM * nbn;
  int gid = pid / gsz;
  int first = gid * GM;
  int rem = nbm - first;
  int g = rem < GM ? rem : GM;
  int pm = first + (pid % g);
  int pn = (pid % gsz) / g;
  int m0 = pm << 7, n0 = pn << 7;
  int w = tid >> 6, lane = tid & 63, l15 = lane & 15, kq = lane >> 4;
  int wm = (w >> 1) << 6, wn = (w & 1) << 6;
  floatx4 acc[4][4];
#pragma unroll
  for (int i = 0; i < 4; ++i)
#pragma unroll
    for (int j = 0; j < 4; ++j) acc[i][j] = (floatx4){0.f, 0.f, 0.f, 0.f};
  int aoff = (wm + l15) * 40 + (kq << 3);
  int boff = (wn + l15) * 40 + (kq << 3);
  for (int k0 = 0; k0 < Kd; k0 += 32) {
#pragma unroll
    for (int l = 0; l < 4; ++l) {
      int idx = tid + (l << 8);
      int row = idx >> 3;
      int c = (idx & 7) << 2;
      uint2 av;
      if (ASRC == 0) {
        av = *(const uint2*)((const u16*)Ap + (size_t)(m0 + row) * Kd + k0 + c);
      } else {
        const float* s; int ld, kk;
        if (k0 < K1) { s = (const float*)Ap; ld = K1; kk = k0; }
        else { s = A2; ld = Kd - K1; kk = k0 - K1; }
        float4 v = *(const float4*)(s + (size_t)(m0 + row) * ld + kk + c);
        av.x = pack2(v.x, v.y);
        av.y = pack2(v.z, v.w);
      }
      *(uint2*)&As[row * 40 + c] = av;
      *(uint2*)&Bs[row * 40 + c] =
          *(const uint2*)(Bt + (size_t)(n0 + row) * Kd + k0 + c);
    }
    __syncthreads();
    short8 af[4], bf[4];
#pragma unroll
    for (int i = 0; i < 4; ++i) {
      af[i] = *(const short8*)&As[aoff + i * (16 * 40)];
      bf[i] = *(const short8*)&Bs[boff + i * (16 * 40)];
    }
#pragma unroll
    for (int mi = 0; mi < 4; ++mi)
#pragma unroll
      for (int ni = 0; ni < 4; ++ni)
        acc[mi][ni] = __builtin_amdgcn_mfma_f32_16x16x32_bf16(
            af[mi], bf[ni], acc[mi][ni], 0, 0, 0);
    __syncthreads();
  }
  float bcol[4];
#pragma unroll
  for (int ni = 0; ni < 4; ++ni) bcol[ni] = bias[n0 + wn + (ni << 4) + l15];
#pragma unroll
  for (int mi = 0; mi < 4; ++mi)
#pragma unroll
    for (int ni = 0; ni < 4; ++ni)
#pragma unroll
      for (int r = 0; r < 4; ++r) {
        int row = m0 + wm + (mi << 4) + (kq << 2) + r;  // C/D: row=(lane>>4)*4+reg
        int col = n0 + wn + (ni << 4) + l15;            //      col=lane&15
        float v = acc[mi][ni][r] + bcol[ni];
        if (TANH) v = tanhf(v);
        if (OUTBF) ((u16*)Cp)[(size_t)row * N + col] = f2bf(v);
        else ((float*)Cp)[(size_t)row * N + col] = v;
      }
}

// f32 [K,N] -> bf16 [N,K] transpose+convert (32x32 LDS tile)
__global__ __launch_bounds__(256) void transpose_cvt(
    const float* __restrict__ in, u16* __restrict__ out, int K, int N) {
  __shared__ float t[32][33];
  int tid = threadIdx.x;
  int bx = blockIdx.x, by = blockIdx.y;  // bx: n-block, by: k-block
  int r = tid >> 3, c4 = (tid & 7) << 2;
  float4 v = *(const float4*)(in + (size_t)(by * 32 + r) * N + bx * 32 + c4);
  t[r][c4 + 0] = v.x; t[r][c4 + 1] = v.y; t[r][c4 + 2] = v.z; t[r][c4 + 3] = v.w;
  __syncthreads();
  uint2 o;
  o.x = pack2(t[c4 + 0][r], t[c4 + 1][r]);
  o.y = pack2(t[c4 + 2][r], t[c4 + 3][r]);
  *(uint2*)(out + (size_t)(bx * 32 + r) * K + by * 32 + c4) = o;
}

// per-row sum of squares; one wave per row
__global__ __launch_bounds__(256) void rownorm_k(
    const float* __restrict__ src, float* __restrict__ out, int cols) {
  int w = threadIdx.x >> 6, lane = threadIdx.x & 63;
  int row = (blockIdx.x << 2) + w;
  const float* p = src + (size_t)row * cols;
  float s = 0.f;
  for (int c = lane; c < cols; c += 64) { float v = p[c]; s = fmaf(v, v, s); }
#pragma unroll
  for (int o = 32; o; o >>= 1) s += __shfl_xor(s, o, 64);
  if (lane == 0) out[row] = s;
}

__global__ void zero_sums(float* p) { if (threadIdx.x < 2) p[threadIdx.x] = 0.f; }

// one wave per row: argmin over 512 dists (first-index tie-break, matching
// jnp.argmin), then commit = ||enc-cb[p]||^2 and recon = ||dx-rect[p]||^2
__global__ __launch_bounds__(256) void argmin_losses(
    const float* __restrict__ dist, const float* __restrict__ enc,
    const float* __restrict__ cb, const float* __restrict__ dx,
    const float* __restrict__ rect, float* __restrict__ prop_out,
    float* __restrict__ sums) {
  int w = threadIdx.x >> 6, lane = threadIdx.x & 63;
  int row = (blockIdx.x << 2) + w;
  const float* drow = dist + (size_t)row * 512;
  float best = 3.4e38f; int bi = 0;
#pragma unroll
  for (int j = 0; j < 8; ++j) {
    int idx = lane + (j << 6);
    float v = drow[idx];
    if (v < best) { best = v; bi = idx; }
  }
#pragma unroll
  for (int o = 32; o; o >>= 1) {
    float ov = __shfl_xor(best, o, 64);
    int oi = __shfl_xor(bi, o, 64);
    if (ov < best || (ov == best && oi < bi)) { best = ov; bi = oi; }
  }
  int p = bi;
  const float* erow = enc + (size_t)row * 1024;
  const float* crow = cb + (size_t)p * 1024;
  const float* xrow = dx + (size_t)row * 1024;
  const float* rrow = rect + (size_t)p * 1024;
  float cs = 0.f, rs = 0.f;
#pragma unroll 4
  for (int c = 0; c < 16; ++c) {
    int col = lane + (c << 6);
    float d1 = erow[col] - crow[col]; cs = fmaf(d1, d1, cs);
    float d2 = xrow[col] - rrow[col]; rs = fmaf(d2, d2, rs);
  }
#pragma unroll
  for (int o = 32; o; o >>= 1) {
    cs += __shfl_xor(cs, o, 64);
    rs += __shfl_xor(rs, o, 64);
  }
  if (lane == 0) {
    atomicAdd(&sums[0], rs);
    atomicAdd(&sums[1], cs);
    prop_out[row] = (float)p;
  }
}

// one wave per row: loss_pi = sum_j 1/(exp(logp)+0.1); loss = loss_pi*total
__global__ __launch_bounds__(256) void finalize_k(
    const float* __restrict__ Aa, const float* __restrict__ mu,
    const float* __restrict__ log_std, const float* __restrict__ sums,
    float* __restrict__ loss, float* __restrict__ losspi,
    float* __restrict__ total_out) {
  int w = threadIdx.x >> 6, lane = threadIdx.x & 63;
  int row = (blockIdx.x << 2) + w;
  // total = recon + vq + commit; vq==commit in forward value
  float total = (sums[0] + 2.0f * sums[1]) * (1.0f / 33554432.0f);
  float s = 0.f;
#pragma unroll
  for (int c = 0; c < 4; ++c) {
    int j = lane + (c << 6);
    float ls = log_std[j];
    float istd = expf(-ls);
    float z = (Aa[(size_t)row * 256 + j] - mu[(size_t)row * 256 + j]) * istd;
    float lp = -0.5f * z * z - ls - 0.91893853320467274f;  // 0.5*log(2*pi)
    s += 1.0f / (expf(lp) + 0.1f);
  }
#pragma unroll
  for (int o = 32; o; o >>= 1) s += __shfl_xor(s, o, 64);
  if (lane == 0) { losspi[row] = s; loss[row] = s * total; }
  if (blockIdx.x == 0 && threadIdx.x == 0) total_out[0] = total;
}

// ---------------------------------------------------------------------------
extern "C" void kernel_launch(void* const* d_in, const int* in_sizes, int n_in,
                              void* d_out, int out_size, void* d_ws,
                              size_t ws_size, hipStream_t stream) {
  (void)in_sizes; (void)n_in; (void)out_size; (void)ws_size;
  const float* X = (const float*)d_in[0];
  const float* DX = (const float*)d_in[1];
  const float* Aa = (const float*)d_in[2];
  const float* enc_w1 = (const float*)d_in[3];
  const float* enc_b1 = (const float*)d_in[4];
  const float* enc_w2 = (const float*)d_in[5];
  const float* enc_b2 = (const float*)d_in[6];
  const float* prenet_w = (const float*)d_in[7];
  const float* prenet_b = (const float*)d_in[8];
  const float* cb = (const float*)d_in[9];
  const float* postnet_w = (const float*)d_in[10];
  const float* postnet_b = (const float*)d_in[11];
  const float* dec_w1 = (const float*)d_in[12];
  const float* dec_b1 = (const float*)d_in[13];
  const float* dec_w2 = (const float*)d_in[14];
  const float* dec_b2 = (const float*)d_in[15];
  const float* dec_w3 = (const float*)d_in[16];
  const float* dec_b3 = (const float*)d_in[17];
  const float* act_w1 = (const float*)d_in[18];
  const float* act_b1 = (const float*)d_in[19];
  const float* act_w2 = (const float*)d_in[20];
  const float* act_b2 = (const float*)d_in[21];
  const float* act_w3 = (const float*)d_in[22];
  const float* act_b3 = (const float*)d_in[23];
  const float* log_std = (const float*)d_in[24];

  float* outf = (float*)d_out;
  const size_t MB = 1ull << 20;
  // Scratch inside the d_out X-slot [65536, 65536+33554432) floats (128 MB);
  // all of it is dead before the final X d2d copy overwrites it.
  char* ox = (char*)(outf + 65536);
  float* dist = (float*)(ox);               // 64 MB, [B,512] f32
  u16* w1T = (u16*)(ox + 64 * MB);          // 6 MB  [2048,1536] bf16
  u16* w2T = (u16*)(ox + 70 * MB);          // 8 MB  [2048,2048] bf16
  u16* w3T = (u16*)(ox + 78 * MB);          // 1 MB  [256,2048] bf16
  float* t0 = (float*)(ox + 79 * MB);       // 2 MB  [512,1024]
  float* d1t = (float*)(ox + 81 * MB);      // 4 MB  [512,2048]
  float* d2t = (float*)(ox + 85 * MB);      // 4 MB  [512,2048]
  float* rect = (float*)(ox + 89 * MB);     // 2 MB  [512,1024] decoder table
  float* mu = (float*)(ox + 91 * MB);       // 32 MB [B,256] f32
  float* cbnorm = (float*)(ox + 123 * MB);  // 2 KB
  float* xnorm = (float*)(ox + 123 * MB + 8192);            // 128 KB
  float* sums = (float*)(ox + 123 * MB + 8192 + 131072);    // 8 B {recon,commit}

  // Workspace (peak 256 MB) with lifetime-based reuse:
  char* wsb = (char*)d_ws;
  float* h2 = (float*)(wsb);              // [0,128) MB, live L5->L6
  float* h1 = (float*)(wsb + 128 * MB);   // [128,192) MB, live L4->L5
  float* enc = (float*)(wsb + 128 * MB);  // [128,256) MB, live L6->argmin (h1 dead)
  u16* a1 = (u16*)(wsb);                  // [0,128) MB bf16 (h2 dead)
  u16* a2 = (u16*)(wsb + 128 * MB);       // [128,256) MB bf16 (enc dead)

  zero_sums<<<1, 64, 0, stream>>>(sums);
  rownorm_k<<<128, 256, 0, stream>>>(cb, cbnorm, 1024);
  transpose_cvt<<<dim3(64, 48), 256, 0, stream>>>(act_w1, w1T, 1536, 2048);
  transpose_cvt<<<dim3(64, 64), 256, 0, stream>>>(act_w2, w2T, 2048, 2048);
  transpose_cvt<<<dim3(8, 64), 256, 0, stream>>>(act_w3, w3T, 2048, 256);

  // encoder chain (fp32; single-level acc — enc errors cancel in argmin)
  gemm_f32_big<1, 0, 0><<<256 * 4, 256, 0, stream>>>(DX, enc_w1, enc_b1, nullptr, h1, 32768, 512, 1024);
  gemm_f32_big<1, 0, 0><<<256 * 8, 256, 0, stream>>>(h1, enc_w2, enc_b2, nullptr, h2, 32768, 1024, 512);
  gemm_f32_big<0, 0, 0><<<256 * 8, 256, 0, stream>>>(h2, prenet_w, prenet_b, nullptr, enc, 32768, 1024, 1024);
  rownorm_k<<<8192, 256, 0, stream>>>(enc, xnorm, 1024);
  // dist = xnorm[m] + cbnorm[n] - 2*enc@cb^T  (fp32, two-level accumulation)
  gemm_f32_big<2, 1, 1><<<256 * 4, 256, 0, stream>>>(enc, cb, cbnorm, xnorm, dist, 32768, 512, 1024);

  // decoder evaluated on the 512 codebook rows only (st_q == quantized fwd)
  gemm_f32<1, 0><<<8 * 16, 256, 0, stream>>>(cb, postnet_w, postnet_b, nullptr, t0, 512, 1024, 1024);
  gemm_f32<1, 0><<<8 * 32, 256, 0, stream>>>(t0, dec_w1, dec_b1, nullptr, d1t, 512, 2048, 1024);
  gemm_f32<1, 0><<<8 * 32, 256, 0, stream>>>(d1t, dec_w2, dec_b2, nullptr, d2t, 512, 2048, 2048);
  gemm_f32<0, 0><<<8 * 16, 256, 0, stream>>>(d2t, dec_w3, dec_b3, nullptr, rect, 512, 1024, 2048);

  // argmin + proposal + recon/commit sums
  argmin_losses<<<8192, 256, 0, stream>>>(dist, enc, cb, DX, rect,
                                          outf + 33619968, sums);

  // actor (bf16 MFMA); A of act1 = [X | dist] via dual-f32 loader
  gemm_bf16<2, 1, 1><<<4096, 256, 0, stream>>>(X, dist, w1T, act_b1, a1, 32768, 2048, 1536, 1024);
  gemm_bf16<0, 1, 1><<<4096, 256, 0, stream>>>(a1, nullptr, w2T, act_b2, a2, 32768, 2048, 2048, 0);
  gemm_bf16<0, 0, 0><<<512, 256, 0, stream>>>(a2, nullptr, w3T, act_b3, mu, 32768, 256, 2048, 0);

  finalize_k<<<8192, 256, 0, stream>>>(Aa, mu, log_std, sums, outf,
                                       outf + 32768, outf + 33652736);
  // X passthrough (overwrites the out-scratch region, must be last)
  hipMemcpyAsync(outf + 65536, X, 134217728ull, hipMemcpyDeviceToDevice, stream);
}

// Round 6
// 3315.115 us; speedup vs baseline: 2.0207x; 1.4834x over previous
//
#include <hip/hip_runtime.h>
#include <stdint.h>

typedef unsigned short u16;
typedef unsigned int u32;
typedef __attribute__((ext_vector_type(8))) short short8;
typedef __attribute__((ext_vector_type(4))) float floatx4;

#define DEV __device__ __forceinline__

DEV u16 f2bf(float f) {
  u32 u = __float_as_uint(f);
  u32 r = (u + 0x7FFFu + ((u >> 16) & 1u)) >> 16;  // RNE
  return (u16)r;
}
DEV float bf2f(u16 h) { return __uint_as_float((u32)h << 16); }
DEV u32 pack2(float a, float b) { return (u32)f2bf(a) | ((u32)f2bf(b) << 16); }

// ---------------------------------------------------------------------------
// fp32 tiled GEMM (small-M path): 64x64 tile, BK=16, 256 threads, 4x4/thread.
// Used only for the 512-row decoder-table GEMMs (grid too small otherwise).
// EPI: 0 = +bias, 1 = tanh(+bias)
// ---------------------------------------------------------------------------
template<int EPI, int BT>
__global__ __launch_bounds__(256) void gemm_f32(
    const float* __restrict__ A, const float* __restrict__ Bsrc,
    const float* __restrict__ bias, const float* __restrict__ xnorm,
    float* __restrict__ C, int M, int N, int Kd) {
  __shared__ float As[16][68];
  __shared__ float Bs[16][68];
  int tid = threadIdx.x;
  int nbm = M >> 6, nbn = N >> 6;
  const int GM = 8;  // L2 swizzle group
  int pid = blockIdx.x;
  int gsz = GM * nbn;
  int gid = pid / gsz;
  int first = gid * GM;
  int rem = nbm - first;
  int g = rem < GM ? rem : GM;
  int pm = first + (pid % g);
  int pn = (pid % gsz) / g;
  int m0 = pm << 6, n0 = pn << 6;
  int ty = tid >> 4, tx = tid & 15;
  int ar = tid >> 2, ak = (tid & 3) << 2;
  float accT[4][4] = {};
  for (int k0 = 0; k0 < Kd; k0 += 16) {
    float4 av = *(const float4*)(A + (size_t)(m0 + ar) * Kd + k0 + ak);
    As[ak + 0][ar] = av.x; As[ak + 1][ar] = av.y;
    As[ak + 2][ar] = av.z; As[ak + 3][ar] = av.w;
    if (BT) {
      float4 bv = *(const float4*)(Bsrc + (size_t)(n0 + ar) * Kd + k0 + ak);
      Bs[ak + 0][ar] = bv.x; Bs[ak + 1][ar] = bv.y;
      Bs[ak + 2][ar] = bv.z; Bs[ak + 3][ar] = bv.w;
    } else {
      int kr = tid >> 4, n4 = (tid & 15) << 2;
      *(float4*)&Bs[kr][n4] = *(const float4*)(Bsrc + (size_t)(k0 + kr) * N + n0 + n4);
    }
    __syncthreads();
    float acc[4][4] = {};
#pragma unroll
    for (int kk = 0; kk < 16; ++kk) {
      float4 a4 = *(float4*)&As[kk][ty << 2];
      float4 b4 = *(float4*)&Bs[kk][tx << 2];
      float ax[4] = {a4.x, a4.y, a4.z, a4.w};
      float bx[4] = {b4.x, b4.y, b4.z, b4.w};
#pragma unroll
      for (int i = 0; i < 4; ++i)
#pragma unroll
        for (int j = 0; j < 4; ++j) acc[i][j] = fmaf(ax[i], bx[j], acc[i][j]);
    }
#pragma unroll
    for (int i = 0; i < 4; ++i)
#pragma unroll
      for (int j = 0; j < 4; ++j) accT[i][j] += acc[i][j];
    __syncthreads();
  }
  int cbi = n0 + (tx << 2);
  float4 bb = *(const float4*)(bias + cbi);
  float bx[4] = {bb.x, bb.y, bb.z, bb.w};
#pragma unroll
  for (int i = 0; i < 4; ++i) {
    int row = m0 + (ty << 2) + i;
    float v[4];
#pragma unroll
    for (int j = 0; j < 4; ++j) {
      float t = accT[i][j] + bx[j];
      v[j] = (EPI == 1) ? tanhf(t) : t;
    }
    float4 o; o.x = v[0]; o.y = v[1]; o.z = v[2]; o.w = v[3];
    *(float4*)(C + (size_t)row * N + cbi) = o;
  }
  (void)xnorm;
}

// ---------------------------------------------------------------------------
// bf16 MFMA GEMM (actor): 128x128 tile, BK=32, 4 waves, each wave 64x64 via
// 4x4 of 16x16x32 mfma. B pre-transposed bf16 [N,K]. LDS stride 40 u16.
// ASRC: 0 = A is bf16 [M,K]; 2 = dual f32 sources (X for k<K1, A2 for k>=K1)
// ---------------------------------------------------------------------------
template<int ASRC, int TANH, int OUTBF>
__global__ __launch_bounds__(256) void gemm_bf16(
    const void* __restrict__ Ap, const float* __restrict__ A2,
    const u16* __restrict__ Bt, const float* __restrict__ bias,
    void* __restrict__ Cp, int M, int N, int Kd, int K1) {
  __shared__ u16 As[128 * 40];
  __shared__ u16 Bs[128 * 40];
  int tid = threadIdx.x;
  int nbm = M >> 7, nbn = N >> 7;
  const int GM = 16;  // L2 swizzle group
  int pid = blockIdx.x;
  int gsz = GM * nbn;
  int gid = pid / gsz;
  int first = gid * GM;
  int rem = nbm - first;
  int g = rem < GM ? rem : GM;
  int pm = first + (pid % g);
  int pn = (pid % gsz) / g;
  int m0 = pm << 7, n0 = pn << 7;
  int w = tid >> 6, lane = tid & 63, l15 = lane & 15, kq = lane >> 4;
  int wm = (w >> 1) << 6, wn = (w & 1) << 6;
  floatx4 acc[4][4];
#pragma unroll
  for (int i = 0; i < 4; ++i)
#pragma unroll
    for (int j = 0; j < 4; ++j) acc[i][j] = (floatx4){0.f, 0.f, 0.f, 0.f};
  int aoff = (wm + l15) * 40 + (kq << 3);
  int boff = (wn + l15) * 40 + (kq << 3);
  for (int k0 = 0; k0 < Kd; k0 += 32) {
#pragma unroll
    for (int l = 0; l < 4; ++l) {
      int idx = tid + (l << 8);
      int row = idx >> 3;
      int c = (idx & 7) << 2;
      uint2 av;
      if (ASRC == 0) {
        av = *(const uint2*)((const u16*)Ap + (size_t)(m0 + row) * Kd + k0 + c);
      } else {
        const float* s; int ld, kk;
        if (k0 < K1) { s = (const float*)Ap; ld = K1; kk = k0; }
        else { s = A2; ld = Kd - K1; kk = k0 - K1; }
        float4 v = *(const float4*)(s + (size_t)(m0 + row) * ld + kk + c);
        av.x = pack2(v.x, v.y);
        av.y = pack2(v.z, v.w);
      }
      *(uint2*)&As[row * 40 + c] = av;
      *(uint2*)&Bs[row * 40 + c] =
          *(const uint2*)(Bt + (size_t)(n0 + row) * Kd + k0 + c);
    }
    __syncthreads();
    short8 af[4], bf[4];
#pragma unroll
    for (int i = 0; i < 4; ++i) {
      af[i] = *(const short8*)&As[aoff + i * (16 * 40)];
      bf[i] = *(const short8*)&Bs[boff + i * (16 * 40)];
    }
#pragma unroll
    for (int mi = 0; mi < 4; ++mi)
#pragma unroll
      for (int ni = 0; ni < 4; ++ni)
        acc[mi][ni] = __builtin_amdgcn_mfma_f32_16x16x32_bf16(
            af[mi], bf[ni], acc[mi][ni], 0, 0, 0);
    __syncthreads();
  }
  float bcol[4];
#pragma unroll
  for (int ni = 0; ni < 4; ++ni) bcol[ni] = bias[n0 + wn + (ni << 4) + l15];
#pragma unroll
  for (int mi = 0; mi < 4; ++mi)
#pragma unroll
    for (int ni = 0; ni < 4; ++ni)
#pragma unroll
      for (int r = 0; r < 4; ++r) {
        int row = m0 + wm + (mi << 4) + (kq << 2) + r;  // C/D: row=(lane>>4)*4+reg
        int col = n0 + wn + (ni << 4) + l15;            //      col=lane&15
        float v = acc[mi][ni][r] + bcol[ni];
        if (TANH) v = tanhf(v);
        if (OUTBF) ((u16*)Cp)[(size_t)row * N + col] = f2bf(v);
        else ((float*)Cp)[(size_t)row * N + col] = v;
      }
}

// ---------------------------------------------------------------------------
// bf16x3 split MFMA GEMM (encoder chain, argmin-grade accuracy):
// A = Ah+Al, B = Bh+Bl (bf16 hi + bf16 residual). Computes
//   acc = Ah*Bh + Al*Bh + Ah*Bl   (fp32 MFMA accum; dropped Al*Bl ~ 2^-18 rel)
// Same tile/fragment structure as gemm_bf16 (proven); 4 LDS arrays, 40 KB.
// AH:  0 = A is f32 [M,K], split on the fly; 1 = A is pre-split bf16 pair
// EPI: 0 = f32 out (+bias); 1 = tanh(+bias) -> hi/lo bf16 pair out;
//      2 = dist epilogue xnorm[m] + cbnorm[n] - 2*acc -> f32
// ---------------------------------------------------------------------------
template<int AH, int EPI>
__global__ __launch_bounds__(256) void gemm_bf16x3(
    const void* __restrict__ Ap, const u16* __restrict__ Alo,
    const u16* __restrict__ Bh, const u16* __restrict__ Bl,
    const float* __restrict__ bias, const float* __restrict__ xnorm,
    void* __restrict__ Cp, u16* __restrict__ Cl,
    int M, int N, int Kd) {
  __shared__ u16 Ash[128 * 40];
  __shared__ u16 Asl[128 * 40];
  __shared__ u16 Bsh[128 * 40];
  __shared__ u16 Bsl[128 * 40];
  int tid = threadIdx.x;
  int nbm = M >> 7, nbn = N >> 7;
  const int GM = 16;  // L2 swizzle group
  int pid = blockIdx.x;
  int gsz = GM * nbn;
  int gid = pid / gsz;
  int first = gid * GM;
  int rem = nbm - first;
  int g = rem < GM ? rem : GM;
  int pm = first + (pid % g);
  int pn = (pid % gsz) / g;
  int m0 = pm << 7, n0 = pn << 7;
  int w = tid >> 6, lane = tid & 63, l15 = lane & 15, kq = lane >> 4;
  int wm = (w >> 1) << 6, wn = (w & 1) << 6;
  floatx4 acc[4][4];
#pragma unroll
  for (int i = 0; i < 4; ++i)
#pragma unroll
    for (int j = 0; j < 4; ++j) acc[i][j] = (floatx4){0.f, 0.f, 0.f, 0.f};
  int aoff = (wm + l15) * 40 + (kq << 3);
  int boff = (wn + l15) * 40 + (kq << 3);
  for (int k0 = 0; k0 < Kd; k0 += 32) {
#pragma unroll
    for (int l = 0; l < 4; ++l) {
      int idx = tid + (l << 8);
      int row = idx >> 3;
      int c = (idx & 7) << 2;
      uint2 ah, al;
      if (AH == 1) {
        ah = *(const uint2*)((const u16*)Ap + (size_t)(m0 + row) * Kd + k0 + c);
        al = *(const uint2*)(Alo + (size_t)(m0 + row) * Kd + k0 + c);
      } else {
        float4 v = *(const float4*)((const float*)Ap + (size_t)(m0 + row) * Kd + k0 + c);
        u16 h0 = f2bf(v.x), h1 = f2bf(v.y), h2 = f2bf(v.z), h3 = f2bf(v.w);
        ah.x = (u32)h0 | ((u32)h1 << 16);
        ah.y = (u32)h2 | ((u32)h3 << 16);
        al.x = pack2(v.x - bf2f(h0), v.y - bf2f(h1));
        al.y = pack2(v.z - bf2f(h2), v.w - bf2f(h3));
      }
      *(uint2*)&Ash[row * 40 + c] = ah;
      *(uint2*)&Asl[row * 40 + c] = al;
      *(uint2*)&Bsh[row * 40 + c] =
          *(const uint2*)(Bh + (size_t)(n0 + row) * Kd + k0 + c);
      *(uint2*)&Bsl[row * 40 + c] =
          *(const uint2*)(Bl + (size_t)(n0 + row) * Kd + k0 + c);
    }
    __syncthreads();
    short8 fah[4], fal[4], fbh[4], fbl[4];
#pragma unroll
    for (int i = 0; i < 4; ++i) {
      fah[i] = *(const short8*)&Ash[aoff + i * (16 * 40)];
      fal[i] = *(const short8*)&Asl[aoff + i * (16 * 40)];
      fbh[i] = *(const short8*)&Bsh[boff + i * (16 * 40)];
      fbl[i] = *(const short8*)&Bsl[boff + i * (16 * 40)];
    }
#pragma unroll
    for (int mi = 0; mi < 4; ++mi)
#pragma unroll
      for (int ni = 0; ni < 4; ++ni) {
        acc[mi][ni] = __builtin_amdgcn_mfma_f32_16x16x32_bf16(
            fah[mi], fbh[ni], acc[mi][ni], 0, 0, 0);
        acc[mi][ni] = __builtin_amdgcn_mfma_f32_16x16x32_bf16(
            fal[mi], fbh[ni], acc[mi][ni], 0, 0, 0);
        acc[mi][ni] = __builtin_amdgcn_mfma_f32_16x16x32_bf16(
            fah[mi], fbl[ni], acc[mi][ni], 0, 0, 0);
      }
    __syncthreads();
  }
  float bcol[4];
#pragma unroll
  for (int ni = 0; ni < 4; ++ni) bcol[ni] = bias[n0 + wn + (ni << 4) + l15];
#pragma unroll
  for (int mi = 0; mi < 4; ++mi)
#pragma unroll
    for (int ni = 0; ni < 4; ++ni)
#pragma unroll
      for (int r = 0; r < 4; ++r) {
        int row = m0 + wm + (mi << 4) + (kq << 2) + r;  // C/D: row=(lane>>4)*4+reg
        int col = n0 + wn + (ni << 4) + l15;            //      col=lane&15
        float a = acc[mi][ni][r];
        if (EPI == 2) {
          ((float*)Cp)[(size_t)row * N + col] = xnorm[row] + bcol[ni] - 2.0f * a;
        } else if (EPI == 1) {
          float t = tanhf(a + bcol[ni]);
          u16 hi = f2bf(t);
          ((u16*)Cp)[(size_t)row * N + col] = hi;
          Cl[(size_t)row * N + col] = f2bf(t - bf2f(hi));
        } else {
          ((float*)Cp)[(size_t)row * N + col] = a + bcol[ni];
        }
      }
}

// f32 [K,N] -> bf16 [N,K] transpose+convert (32x32 LDS tile), actor weights
__global__ __launch_bounds__(256) void transpose_cvt(
    const float* __restrict__ in, u16* __restrict__ out, int K, int N) {
  __shared__ float t[32][33];
  int tid = threadIdx.x;
  int bx = blockIdx.x, by = blockIdx.y;  // bx: n-block, by: k-block
  int r = tid >> 3, c4 = (tid & 7) << 2;
  float4 v = *(const float4*)(in + (size_t)(by * 32 + r) * N + bx * 32 + c4);
  t[r][c4 + 0] = v.x; t[r][c4 + 1] = v.y; t[r][c4 + 2] = v.z; t[r][c4 + 3] = v.w;
  __syncthreads();
  uint2 o;
  o.x = pack2(t[c4 + 0][r], t[c4 + 1][r]);
  o.y = pack2(t[c4 + 2][r], t[c4 + 3][r]);
  *(uint2*)(out + (size_t)(bx * 32 + r) * K + by * 32 + c4) = o;
}

// f32 [K,N] -> (hi,lo) bf16 [N,K] transpose+split (encoder weights)
__global__ __launch_bounds__(256) void transpose_cvt_hl(
    const float* __restrict__ in, u16* __restrict__ oh, u16* __restrict__ ol,
    int K, int N) {
  __shared__ float t[32][33];
  int tid = threadIdx.x;
  int bx = blockIdx.x, by = blockIdx.y;  // bx: n-block, by: k-block
  int r = tid >> 3, c4 = (tid & 7) << 2;
  float4 v = *(const float4*)(in + (size_t)(by * 32 + r) * N + bx * 32 + c4);
  t[r][c4 + 0] = v.x; t[r][c4 + 1] = v.y; t[r][c4 + 2] = v.z; t[r][c4 + 3] = v.w;
  __syncthreads();
  float f0 = t[c4 + 0][r], f1 = t[c4 + 1][r], f2 = t[c4 + 2][r], f3 = t[c4 + 3][r];
  u16 h0 = f2bf(f0), h1 = f2bf(f1), h2 = f2bf(f2), h3 = f2bf(f3);
  uint2 vh, vl;
  vh.x = (u32)h0 | ((u32)h1 << 16);
  vh.y = (u32)h2 | ((u32)h3 << 16);
  vl.x = pack2(f0 - bf2f(h0), f1 - bf2f(h1));
  vl.y = pack2(f2 - bf2f(h2), f3 - bf2f(h3));
  size_t off = (size_t)(bx * 32 + r) * K + by * 32 + c4;
  *(uint2*)(oh + off) = vh;
  *(uint2*)(ol + off) = vl;
}

// elementwise f32 -> (hi,lo) bf16 split (codebook; already [N,K] layout)
__global__ __launch_bounds__(256) void split_bf16(
    const float* __restrict__ in, u16* __restrict__ oh, u16* __restrict__ ol,
    int n4) {
  int i = (blockIdx.x * 256 + threadIdx.x) << 2;
  if (i >= n4) return;
  float4 v = *(const float4*)(in + i);
  u16 h0 = f2bf(v.x), h1 = f2bf(v.y), h2 = f2bf(v.z), h3 = f2bf(v.w);
  uint2 vh, vl;
  vh.x = (u32)h0 | ((u32)h1 << 16);
  vh.y = (u32)h2 | ((u32)h3 << 16);
  vl.x = pack2(v.x - bf2f(h0), v.y - bf2f(h1));
  vl.y = pack2(v.z - bf2f(h2), v.w - bf2f(h3));
  *(uint2*)(oh + i) = vh;
  *(uint2*)(ol + i) = vl;
}

// per-row sum of squares; one wave per row
__global__ __launch_bounds__(256) void rownorm_k(
    const float* __restrict__ src, float* __restrict__ out, int cols) {
  int w = threadIdx.x >> 6, lane = threadIdx.x & 63;
  int row = (blockIdx.x << 2) + w;
  const float* p = src + (size_t)row * cols;
  float s = 0.f;
  for (int c = lane; c < cols; c += 64) { float v = p[c]; s = fmaf(v, v, s); }
#pragma unroll
  for (int o = 32; o; o >>= 1) s += __shfl_xor(s, o, 64);
  if (lane == 0) out[row] = s;
}

__global__ void zero_sums(float* p) { if (threadIdx.x < 2) p[threadIdx.x] = 0.f; }

// one wave per row: argmin over 512 dists (first-index tie-break, matching
// jnp.argmin), then commit = ||enc-cb[p]||^2 and recon = ||dx-rect[p]||^2
__global__ __launch_bounds__(256) void argmin_losses(
    const float* __restrict__ dist, const float* __restrict__ enc,
    const float* __restrict__ cb, const float* __restrict__ dx,
    const float* __restrict__ rect, float* __restrict__ prop_out,
    float* __restrict__ sums) {
  int w = threadIdx.x >> 6, lane = threadIdx.x & 63;
  int row = (blockIdx.x << 2) + w;
  const float* drow = dist + (size_t)row * 512;
  float best = 3.4e38f; int bi = 0;
#pragma unroll
  for (int j = 0; j < 8; ++j) {
    int idx = lane + (j << 6);
    float v = drow[idx];
    if (v < best) { best = v; bi = idx; }
  }
#pragma unroll
  for (int o = 32; o; o >>= 1) {
    float ov = __shfl_xor(best, o, 64);
    int oi = __shfl_xor(bi, o, 64);
    if (ov < best || (ov == best && oi < bi)) { best = ov; bi = oi; }
  }
  int p = bi;
  const float* erow = enc + (size_t)row * 1024;
  const float* crow = cb + (size_t)p * 1024;
  const float* xrow = dx + (size_t)row * 1024;
  const float* rrow = rect + (size_t)p * 1024;
  float cs = 0.f, rs = 0.f;
#pragma unroll 4
  for (int c = 0; c < 16; ++c) {
    int col = lane + (c << 6);
    float d1 = erow[col] - crow[col]; cs = fmaf(d1, d1, cs);
    float d2 = xrow[col] - rrow[col]; rs = fmaf(d2, d2, rs);
  }
#pragma unroll
  for (int o = 32; o; o >>= 1) {
    cs += __shfl_xor(cs, o, 64);
    rs += __shfl_xor(rs, o, 64);
  }
  if (lane == 0) {
    atomicAdd(&sums[0], rs);
    atomicAdd(&sums[1], cs);
    prop_out[row] = (float)p;
  }
}

// one wave per row: loss_pi = sum_j 1/(exp(logp)+0.1); loss = loss_pi*total
__global__ __launch_bounds__(256) void finalize_k(
    const float* __restrict__ Aa, const float* __restrict__ mu,
    const float* __restrict__ log_std, const float* __restrict__ sums,
    float* __restrict__ loss, float* __restrict__ losspi,
    float* __restrict__ total_out) {
  int w = threadIdx.x >> 6, lane = threadIdx.x & 63;
  int row = (blockIdx.x << 2) + w;
  // total = recon + vq + commit; vq==commit in forward value
  float total = (sums[0] + 2.0f * sums[1]) * (1.0f / 33554432.0f);
  float s = 0.f;
#pragma unroll
  for (int c = 0; c < 4; ++c) {
    int j = lane + (c << 6);
    float ls = log_std[j];
    float istd = expf(-ls);
    float z = (Aa[(size_t)row * 256 + j] - mu[(size_t)row * 256 + j]) * istd;
    float lp = -0.5f * z * z - ls - 0.91893853320467274f;  // 0.5*log(2*pi)
    s += 1.0f / (expf(lp) + 0.1f);
  }
#pragma unroll
  for (int o = 32; o; o >>= 1) s += __shfl_xor(s, o, 64);
  if (lane == 0) { losspi[row] = s; loss[row] = s * total; }
  if (blockIdx.x == 0 && threadIdx.x == 0) total_out[0] = total;
}

// ---------------------------------------------------------------------------
extern "C" void kernel_launch(void* const* d_in, const int* in_sizes, int n_in,
                              void* d_out, int out_size, void* d_ws,
                              size_t ws_size, hipStream_t stream) {
  (void)in_sizes; (void)n_in; (void)out_size; (void)ws_size;
  const float* X = (const float*)d_in[0];
  const float* DX = (const float*)d_in[1];
  const float* Aa = (const float*)d_in[2];
  const float* enc_w1 = (const float*)d_in[3];
  const float* enc_b1 = (const float*)d_in[4];
  const float* enc_w2 = (const float*)d_in[5];
  const float* enc_b2 = (const float*)d_in[6];
  const float* prenet_w = (const float*)d_in[7];
  const float* prenet_b = (const float*)d_in[8];
  const float* cb = (const float*)d_in[9];
  const float* postnet_w = (const float*)d_in[10];
  const float* postnet_b = (const float*)d_in[11];
  const float* dec_w1 = (const float*)d_in[12];
  const float* dec_b1 = (const float*)d_in[13];
  const float* dec_w2 = (const float*)d_in[14];
  const float* dec_b2 = (const float*)d_in[15];
  const float* dec_w3 = (const float*)d_in[16];
  const float* dec_b3 = (const float*)d_in[17];
  const float* act_w1 = (const float*)d_in[18];
  const float* act_b1 = (const float*)d_in[19];
  const float* act_w2 = (const float*)d_in[20];
  const float* act_b2 = (const float*)d_in[21];
  const float* act_w3 = (const float*)d_in[22];
  const float* act_b3 = (const float*)d_in[23];
  const float* log_std = (const float*)d_in[24];

  float* outf = (float*)d_out;
  const size_t MB = 1ull << 20;
  // Scratch inside the d_out X-slot [65536, 65536+33554432) floats (128 MB);
  // all of it is dead before the final X d2d copy overwrites it.
  char* ox = (char*)(outf + 65536);
  float* dist = (float*)(ox);               // 64 MB, [B,512] f32
  u16* w1T = (u16*)(ox + 64 * MB);          // 6 MB  [2048,1536] bf16 (actor)
  u16* w2T = (u16*)(ox + 70 * MB);          // 8 MB  [2048,2048] bf16 (actor)
  u16* w3T = (u16*)(ox + 78 * MB);          // 1 MB  [256,2048] bf16 (actor)
  // encoder weight splits live [79,89) MB until their GEMM completes; the
  // decoder-table buffers below reuse the same window afterwards (disjoint
  // lifetimes in stream order).
  u16* w1hT = (u16*)(ox + 79 * MB);         // 1 MB [512,1024]
  u16* w1lT = (u16*)(ox + 80 * MB);         // 1 MB
  u16* w2hT = (u16*)(ox + 81 * MB);         // 1 MB [1024,512]
  u16* w2lT = (u16*)(ox + 82 * MB);         // 1 MB
  u16* pwhT = (u16*)(ox + 83 * MB);         // 2 MB [1024,1024]
  u16* pwlT = (u16*)(ox + 85 * MB);         // 2 MB
  u16* cbh = (u16*)(ox + 87 * MB);          // 1 MB [512,1024]
  u16* cbl = (u16*)(ox + 88 * MB);          // 1 MB
  float* t0 = (float*)(ox + 79 * MB);       // 2 MB  [512,1024]  (after dist)
  float* d1t = (float*)(ox + 81 * MB);      // 4 MB  [512,2048]
  float* d2t = (float*)(ox + 85 * MB);      // 4 MB  [512,2048]
  float* rect = (float*)(ox + 89 * MB);     // 2 MB  [512,1024] decoder table
  float* mu = (float*)(ox + 91 * MB);       // 32 MB [B,256] f32
  float* cbnorm = (float*)(ox + 123 * MB);  // 2 KB
  float* xnorm = (float*)(ox + 123 * MB + 8192);            // 128 KB
  float* sums = (float*)(ox + 123 * MB + 8192 + 131072);    // 8 B {recon,commit}

  // Workspace (peak 256 MB) with lifetime-based reuse:
  char* wsb = (char*)d_ws;
  u16* h2h = (u16*)(wsb);                  // [0,64) MB, live enc2->prenet
  u16* h2l = (u16*)(wsb + 64 * MB);        // [64,128) MB
  u16* h1h = (u16*)(wsb + 128 * MB);       // [128,160) MB, live enc1->enc2
  u16* h1l = (u16*)(wsb + 160 * MB);       // [160,192) MB
  float* enc = (float*)(wsb + 128 * MB);   // [128,256) MB, live prenet->argmin (h1 dead)
  u16* a1 = (u16*)(wsb);                   // [0,128) MB bf16 (h2 dead)
  u16* a2 = (u16*)(wsb + 128 * MB);        // [128,256) MB bf16 (enc dead)

  zero_sums<<<1, 64, 0, stream>>>(sums);
  rownorm_k<<<128, 256, 0, stream>>>(cb, cbnorm, 1024);
  transpose_cvt<<<dim3(64, 48), 256, 0, stream>>>(act_w1, w1T, 1536, 2048);
  transpose_cvt<<<dim3(64, 64), 256, 0, stream>>>(act_w2, w2T, 2048, 2048);
  transpose_cvt<<<dim3(8, 64), 256, 0, stream>>>(act_w3, w3T, 2048, 256);
  // encoder weight hi/lo splits (transposed to [N,K])
  transpose_cvt_hl<<<dim3(16, 32), 256, 0, stream>>>(enc_w1, w1hT, w1lT, 1024, 512);
  transpose_cvt_hl<<<dim3(32, 16), 256, 0, stream>>>(enc_w2, w2hT, w2lT, 512, 1024);
  transpose_cvt_hl<<<dim3(32, 32), 256, 0, stream>>>(prenet_w, pwhT, pwlT, 1024, 1024);
  split_bf16<<<512, 256, 0, stream>>>(cb, cbh, cbl, 524288);

  // encoder chain (bf16x3 MFMA, ~fp32-grade accuracy)
  gemm_bf16x3<0, 1><<<1024, 256, 0, stream>>>(DX, nullptr, w1hT, w1lT, enc_b1,
                                              nullptr, h1h, h1l, 32768, 512, 1024);
  gemm_bf16x3<1, 1><<<2048, 256, 0, stream>>>(h1h, h1l, w2hT, w2lT, enc_b2,
                                              nullptr, h2h, h2l, 32768, 1024, 512);
  gemm_bf16x3<1, 0><<<2048, 256, 0, stream>>>(h2h, h2l, pwhT, pwlT, prenet_b,
                                              nullptr, enc, nullptr, 32768, 1024, 1024);
  rownorm_k<<<8192, 256, 0, stream>>>(enc, xnorm, 1024);
  // dist = xnorm[m] + cbnorm[n] - 2*enc@cb^T
  gemm_bf16x3<0, 2><<<1024, 256, 0, stream>>>(enc, nullptr, cbh, cbl, cbnorm,
                                              xnorm, dist, nullptr, 32768, 512, 1024);

  // decoder evaluated on the 512 codebook rows only (st_q == quantized fwd)
  gemm_f32<1, 0><<<8 * 16, 256, 0, stream>>>(cb, postnet_w, postnet_b, nullptr, t0, 512, 1024, 1024);
  gemm_f32<1, 0><<<8 * 32, 256, 0, stream>>>(t0, dec_w1, dec_b1, nullptr, d1t, 512, 2048, 1024);
  gemm_f32<1, 0><<<8 * 32, 256, 0, stream>>>(d1t, dec_w2, dec_b2, nullptr, d2t, 512, 2048, 2048);
  gemm_f32<0, 0><<<8 * 16, 256, 0, stream>>>(d2t, dec_w3, dec_b3, nullptr, rect, 512, 1024, 2048);

  // argmin + proposal + recon/commit sums
  argmin_losses<<<8192, 256, 0, stream>>>(dist, enc, cb, DX, rect,
                                          outf + 33619968, sums);

  // actor (bf16 MFMA); A of act1 = [X | dist] via dual-f32 loader
  gemm_bf16<2, 1, 1><<<4096, 256, 0, stream>>>(X, dist, w1T, act_b1, a1, 32768, 2048, 1536, 1024);
  gemm_bf16<0, 1, 1><<<4096, 256, 0, stream>>>(a1, nullptr, w2T, act_b2, a2, 32768, 2048, 2048, 0);
  gemm_bf16<0, 0, 0><<<512, 256, 0, stream>>>(a2, nullptr, w3T, act_b3, mu, 32768, 256, 2048, 0);

  finalize_k<<<8192, 256, 0, stream>>>(Aa, mu, log_std, sums, outf,
                                       outf + 32768, outf + 33652736);
  // X passthrough (overwrites the out-scratch region, must be last)
  hipMemcpyAsync(outf + 65536, X, 134217728ull, hipMemcpyDeviceToDevice, stream);
}